// Round 6
// baseline (305.560 us; speedup 1.0000x reference)
//
#include <hip/hip_runtime.h>

#define H 512
#define V 50000
#define NBLK 512
#define NTHR 1024

typedef float fx4 __attribute__((ext_vector_type(4)));

__device__ __forceinline__ float sigmoidf(float x) {
    return 1.0f / (1.0f + __expf(-x));
}

__device__ __forceinline__ float wave_reduce(float v) {
    #pragma unroll
    for (int m = 32; m >= 1; m >>= 1)
        v += __shfl_xor(v, m, 64);
    return v;
}

__device__ __forceinline__ float dot4(fx4 a, fx4 b) {
    return a.x * b.x + a.y * b.y + a.z * b.z + a.w * b.w;
}

__device__ __forceinline__ fx4 ntload4(const float* p) {
    return __builtin_nontemporal_load((const fx4*)p);
}

__device__ __forceinline__ fx4 ld4(const float* p) {
    return *(const fx4*)p;
}

// Single fused kernel. 512 blocks x 1024 threads = exactly 2 blocks/CU
// (launch_bounds caps VGPR<=64, LDS 6.2KB) -> grid == resident capacity, so a
// software barrier is deadlock-free regardless of dispatch order.
// Prologue: every block redundantly computes h3_new (W_h3 1MB, L2-broadcast).
// Stage B: block j -> h_new[j] (fused hypernet matvec over W_ctx, 512MB).
// Barrier (atomic counter in ws).
// Stage C: block j -> 98 logits rows from fc_W (100MB).
__global__ __launch_bounds__(NTHR, 8) void fused(
    const int* __restrict__ inputX, const float* __restrict__ intervalX,
    const float* __restrict__ h, const float* __restrict__ h3,
    const float* __restrict__ emb,
    const float* __restrict__ W_h3, const float* __restrict__ b_h3,
    const float* __restrict__ W_int, const float* __restrict__ b_int,
    const float* __restrict__ W_ctx, const float* __restrict__ b_ctx,
    const float* __restrict__ b_ictx,
    const float* __restrict__ Wx, const float* __restrict__ Bx,
    const float* __restrict__ fc_W, const float* __restrict__ fc_b,
    float* __restrict__ out, int* __restrict__ cnt)
{
    __shared__ float sh3[H];
    __shared__ float sh[H];
    __shared__ float sbc[H];
    __shared__ float red[16];

    const int tid  = threadIdx.x;
    const int wv   = tid >> 6;
    const int lane = tid & 63;
    const int j    = blockIdx.x;
    const size_t base = (size_t)j * H;

    // stage-B operand staging (synced by the prologue's __syncthreads)
    if (tid < H) sh[tid] = h[tid];
    else { const int t = tid - H; sbc[t] = b_ctx[base + t]; }

    // ---- Prologue: h3_new computed redundantly per block (identical fp order
    // in every block -> identical values). Block 0 also writes it to out.
    {
        const float ivx = intervalX[0];
        const fx4 x0 = ld4(h3 + lane * 4);
        const fx4 x1 = ld4(h3 + 256 + lane * 4);
        #pragma unroll 4
        for (int i = 0; i < 32; ++i) {
            const int k = wv * 32 + i;
            const float* Wrow = W_h3 + (size_t)k * H;
            fx4 a0 = ld4(Wrow + lane * 4);
            fx4 a1 = ld4(Wrow + 256 + lane * 4);
            float p = wave_reduce(dot4(a0, x0) + dot4(a1, x1));
            if (lane == 0) {
                float v = sigmoidf(p + ivx * W_int[k] + b_int[k] + b_h3[k]);
                sh3[k] = v;
                if (j == 0) out[V + H + k] = v;
            }
        }
    }
    __syncthreads();

    // ---- Stage B ----
    const fx4 x0 = ld4(sh3 + lane * 4);
    const fx4 x1 = ld4(sh3 + 256 + lane * 4);

    float acc = 0.0f;
    if (wv == 0) {
        // folded input term: dot(x_emb, Wx[j,:]) + Bx[j] + b_ictx[j]
        const float* Wxrow = Wx + (size_t)j * H;
        const float* e = emb + (size_t)inputX[0] * H;
        fx4 a0 = ld4(Wxrow + lane * 4);
        fx4 a1 = ld4(Wxrow + 256 + lane * 4);
        fx4 e0 = ld4(e + lane * 4);
        fx4 e1 = ld4(e + 256 + lane * 4);
        float p = wave_reduce(dot4(a0, e0) + dot4(a1, e1));
        acc += p + Bx[j] + b_ictx[j];   // only lane0's red[] entry is used
    }

    if ((j & 3) == 0) {
        // LLC-resident quarter: plain loads
        #pragma unroll 4
        for (int i = 0; i < 32; ++i) {
            const int k = wv * 32 + i;
            const float* Wrow = W_ctx + (base + (size_t)k) * H;
            fx4 a0 = ld4(Wrow + lane * 4);
            fx4 a1 = ld4(Wrow + 256 + lane * 4);
            float p = wave_reduce(dot4(a0, x0) + dot4(a1, x1));
            acc += sh[k] * sigmoidf(p + sbc[k]);
        }
    } else {
        // streaming three-quarters: nt (evict-first) loads
        #pragma unroll 4
        for (int i = 0; i < 32; ++i) {
            const int k = wv * 32 + i;
            const float* Wrow = W_ctx + (base + (size_t)k) * H;
            fx4 a0 = ntload4(Wrow + lane * 4);
            fx4 a1 = ntload4(Wrow + 256 + lane * 4);
            float p = wave_reduce(dot4(a0, x0) + dot4(a1, x1));
            acc += sh[k] * sigmoidf(p + sbc[k]);
        }
    }

    if (lane == 0) red[wv] = acc;
    __syncthreads();

    // ---- Software grid barrier (producer: release; consumer: acquire) ----
    if (tid == 0) {
        float t = 0.0f;
        #pragma unroll
        for (int w = 0; w < 16; ++w) t += red[w];
        out[V + j] = sigmoidf(t);
        __threadfence();
        __hip_atomic_fetch_add(cnt, 1, __ATOMIC_RELEASE, __HIP_MEMORY_SCOPE_AGENT);
        while (__hip_atomic_load(cnt, __ATOMIC_RELAXED, __HIP_MEMORY_SCOPE_AGENT) < NBLK) {
            __builtin_amdgcn_s_sleep(2);
        }
    }
    __syncthreads();
    __threadfence();   // invalidate stale L1/L2 views of h_new on this CU

    // ---- Stage C ----
    // reuse sh3 for h_new (all sh3 readers finished before the barrier)
    if (tid < H) sh3[tid] = out[V + tid];
    __syncthreads();

    const fx4 y0 = ld4(sh3 + lane * 4);
    const fx4 y1 = ld4(sh3 + 256 + lane * 4);

    const int rbeg = j * 98;            // 512*98 = 50176 >= 50000
    for (int t = wv; t < 98; t += 16) {
        const int v = rbeg + t;
        if (v < V) {
            const float* Wrow = fc_W + (size_t)v * H;
            fx4 a0 = ld4(Wrow + lane * 4);
            fx4 a1 = ld4(Wrow + 256 + lane * 4);
            float p = wave_reduce(dot4(a0, y0) + dot4(a1, y1));
            if (lane == 0) out[v] = p + fc_b[v];
        }
    }
}

extern "C" void kernel_launch(void* const* d_in, const int* in_sizes, int n_in,
                              void* d_out, int out_size, void* d_ws, size_t ws_size,
                              hipStream_t stream) {
    const int*   inputX    = (const int*)d_in[0];
    const float* intervalX = (const float*)d_in[3];
    const float* h         = (const float*)d_in[4];
    const float* h3        = (const float*)d_in[5];
    const float* emb       = (const float*)d_in[6];
    const float* W_h3      = (const float*)d_in[7];
    const float* b_h3      = (const float*)d_in[8];
    const float* W_int     = (const float*)d_in[9];
    const float* b_int     = (const float*)d_in[10];
    const float* W_ctx     = (const float*)d_in[11];
    const float* b_ctx     = (const float*)d_in[12];
    const float* b_ictx    = (const float*)d_in[13];
    const float* Wx        = (const float*)d_in[14];
    const float* Bx        = (const float*)d_in[15];
    const float* fc_W      = (const float*)d_in[16];
    const float* fc_b      = (const float*)d_in[17];

    float* out = (float*)d_out;          // [logits(50000) | h_new(512) | h3_new(512)]
    int*   cnt = (int*)d_ws;             // barrier counter

    hipMemsetAsync(d_ws, 0, 64, stream); // graph-safe: async memset node

    fused<<<NBLK, NTHR, 0, stream>>>(inputX, intervalX, h, h3, emb,
                                     W_h3, b_h3, W_int, b_int,
                                     W_ctx, b_ctx, b_ictx, Wx, Bx,
                                     fc_W, fc_b, out, cnt);
}

// Round 7
// 108.428 us; speedup vs baseline: 2.8181x; 2.8181x over previous
//
#include <hip/hip_runtime.h>

#define H 512
#define V 50000

typedef float fx4 __attribute__((ext_vector_type(4)));

__device__ __forceinline__ float sigmoidf(float x) {
    return 1.0f / (1.0f + __expf(-x));
}

__device__ __forceinline__ float dot4(fx4 a, fx4 b) {
    return a.x * b.x + a.y * b.y + a.z * b.z + a.w * b.w;
}

__device__ __forceinline__ fx4 ntload4(const float* p) {
    return __builtin_nontemporal_load((const fx4*)p);
}

__device__ __forceinline__ fx4 ld4(const float* p) {
    return *(const fx4*)p;
}

// Kernel A: h3_new only. 256 blocks x 128 threads (2 waves), wave handles one row.
__global__ __launch_bounds__(128) void kA(
    const float* __restrict__ intervalX, const float* __restrict__ h3,
    const float* __restrict__ W_h3, const float* __restrict__ b_h3,
    const float* __restrict__ W_int, const float* __restrict__ b_int,
    float* __restrict__ out)
{
    const int tid  = threadIdx.x;
    const int wv   = tid >> 6;
    const int lane = tid & 63;
    const int r    = blockIdx.x * 2 + wv;

    const float* Wrow = W_h3 + (size_t)r * H;
    fx4 a0 = ld4(Wrow + lane * 4);
    fx4 a1 = ld4(Wrow + 256 + lane * 4);
    fx4 x0 = ld4(h3 + lane * 4);
    fx4 x1 = ld4(h3 + 256 + lane * 4);
    float p = dot4(a0, x0) + dot4(a1, x1);
    #pragma unroll
    for (int m = 32; m >= 1; m >>= 1) p += __shfl_xor(p, m, 64);

    if (lane == 0) {
        float pre = p + intervalX[0] * W_int[r] + b_int[r] + b_h3[r];
        out[V + H + r] = sigmoidf(pre);
    }
}

// Kernel B: fused hypernet + gated update (+ folded x_emb@Wx.T term).
// block j: h_new[j] = sigmoid( dot(x_emb,Wx[j]) + Bx[j] + b_ictx[j]
//                              + sum_k h[k]*sigmoid(dot(h3n, W_ctx[j*512+k,:]) + b_ctx[j*512+k]) )
// 512 blocks x 1024 threads (16 waves): wave w handles rows k = w*32 .. w*32+31,
// hand-unrolled x2: 4 loads in flight, 2 interleaved butterfly reduces.
// LLC: (j&3)==0 plain loads (128MB resident across replays), rest nt streaming.
__global__ __launch_bounds__(1024) void kB(
    const int* __restrict__ inputX, const float* __restrict__ emb,
    const float* __restrict__ h, const float* __restrict__ W_ctx,
    const float* __restrict__ b_ctx, const float* __restrict__ h3n,
    const float* __restrict__ Wx, const float* __restrict__ Bx,
    const float* __restrict__ b_ictx, float* __restrict__ out)
{
    __shared__ float sh3[H];
    __shared__ float sh[H];
    __shared__ float sbc[H];
    __shared__ float red[16];

    const int tid = threadIdx.x;
    const int j   = blockIdx.x;
    const size_t base = (size_t)j * H;

    if (tid < H) {
        sh3[tid] = h3n[tid];
    } else {
        const int t = tid - H;
        sh[t]  = h[t];
        sbc[t] = b_ctx[base + t];
    }
    __syncthreads();

    const int wv   = tid >> 6;
    const int lane = tid & 63;

    const fx4 x0 = ld4(sh3 + lane * 4);
    const fx4 x1 = ld4(sh3 + 256 + lane * 4);

    float acc = 0.0f;

    if (wv == 0) {
        // folded input term: dot(x_emb, Wx[j,:]) + Bx[j] + b_ictx[j]
        const float* Wxrow = Wx + (size_t)j * H;
        const float* e = emb + (size_t)inputX[0] * H;
        fx4 a0 = ld4(Wxrow + lane * 4);
        fx4 a1 = ld4(Wxrow + 256 + lane * 4);
        float p = dot4(a0, ld4(e + lane * 4)) + dot4(a1, ld4(e + 256 + lane * 4));
        #pragma unroll
        for (int m = 32; m >= 1; m >>= 1) p += __shfl_xor(p, m, 64);
        acc += p + Bx[j] + b_ictx[j];   // only lane0's red[] entry is used
    }

    const int kbase = wv * 32;
    if ((j & 3) == 0) {
        // LLC-resident quarter: plain loads
        for (int i = 0; i < 32; i += 2) {
            const int k0 = kbase + i;
            const float* W0 = W_ctx + (base + (size_t)k0) * H;
            const float* W1 = W0 + H;
            fx4 a0 = ld4(W0 + lane * 4);
            fx4 a1 = ld4(W0 + 256 + lane * 4);
            fx4 b0 = ld4(W1 + lane * 4);
            fx4 b1 = ld4(W1 + 256 + lane * 4);
            float p = dot4(a0, x0) + dot4(a1, x1);
            float q = dot4(b0, x0) + dot4(b1, x1);
            #pragma unroll
            for (int m = 32; m >= 1; m >>= 1) {
                p += __shfl_xor(p, m, 64);
                q += __shfl_xor(q, m, 64);
            }
            acc += sh[k0]     * sigmoidf(p + sbc[k0]);
            acc += sh[k0 + 1] * sigmoidf(q + sbc[k0 + 1]);
        }
    } else {
        // streaming three-quarters: nt (evict-first) loads
        for (int i = 0; i < 32; i += 2) {
            const int k0 = kbase + i;
            const float* W0 = W_ctx + (base + (size_t)k0) * H;
            const float* W1 = W0 + H;
            fx4 a0 = ntload4(W0 + lane * 4);
            fx4 a1 = ntload4(W0 + 256 + lane * 4);
            fx4 b0 = ntload4(W1 + lane * 4);
            fx4 b1 = ntload4(W1 + 256 + lane * 4);
            float p = dot4(a0, x0) + dot4(a1, x1);
            float q = dot4(b0, x0) + dot4(b1, x1);
            #pragma unroll
            for (int m = 32; m >= 1; m >>= 1) {
                p += __shfl_xor(p, m, 64);
                q += __shfl_xor(q, m, 64);
            }
            acc += sh[k0]     * sigmoidf(p + sbc[k0]);
            acc += sh[k0 + 1] * sigmoidf(q + sbc[k0 + 1]);
        }
    }

    if (lane == 0) red[wv] = acc;
    __syncthreads();

    if (tid == 0) {
        float t = 0.0f;
        #pragma unroll
        for (int w = 0; w < 16; ++w) t += red[w];
        out[V + j] = sigmoidf(t);
    }
}

// Kernel C: logits = h_new @ fc_W.T + fc_b.
// 6250 blocks x 256 threads: block handles 8 rows, wave w rows 8b+2w .. +1.
// Plain loads: fc_W (100MB) candidates for LLC residency across replays.
__global__ __launch_bounds__(256) void kC(
    const float* __restrict__ h_new, const float* __restrict__ fc_W,
    const float* __restrict__ fc_b, float* __restrict__ out)
{
    __shared__ float shn[H];
    const int tid = threadIdx.x;
    shn[tid]       = h_new[tid];
    shn[tid + 256] = h_new[tid + 256];
    __syncthreads();

    const int wv   = tid >> 6;
    const int lane = tid & 63;
    const fx4 x0 = ld4(shn + lane * 4);
    const fx4 x1 = ld4(shn + 256 + lane * 4);

    const int v0 = blockIdx.x * 8 + wv * 2;   // 6250*8 = 50000 exactly
    const float* W0 = fc_W + (size_t)v0 * H;
    const float* W1 = W0 + H;
    fx4 a0 = ld4(W0 + lane * 4);
    fx4 a1 = ld4(W0 + 256 + lane * 4);
    fx4 b0 = ld4(W1 + lane * 4);
    fx4 b1 = ld4(W1 + 256 + lane * 4);
    float p = dot4(a0, x0) + dot4(a1, x1);
    float q = dot4(b0, x0) + dot4(b1, x1);
    #pragma unroll
    for (int m = 32; m >= 1; m >>= 1) {
        p += __shfl_xor(p, m, 64);
        q += __shfl_xor(q, m, 64);
    }
    if (lane == 0) {
        out[v0]     = p + fc_b[v0];
        out[v0 + 1] = q + fc_b[v0 + 1];
    }
}

extern "C" void kernel_launch(void* const* d_in, const int* in_sizes, int n_in,
                              void* d_out, int out_size, void* d_ws, size_t ws_size,
                              hipStream_t stream) {
    const int*   inputX    = (const int*)d_in[0];
    const float* intervalX = (const float*)d_in[3];
    const float* h         = (const float*)d_in[4];
    const float* h3        = (const float*)d_in[5];
    const float* emb       = (const float*)d_in[6];
    const float* W_h3      = (const float*)d_in[7];
    const float* b_h3      = (const float*)d_in[8];
    const float* W_int     = (const float*)d_in[9];
    const float* b_int     = (const float*)d_in[10];
    const float* W_ctx     = (const float*)d_in[11];
    const float* b_ctx     = (const float*)d_in[12];
    const float* b_ictx    = (const float*)d_in[13];
    const float* Wx        = (const float*)d_in[14];
    const float* Bx        = (const float*)d_in[15];
    const float* fc_W      = (const float*)d_in[16];
    const float* fc_b      = (const float*)d_in[17];

    float* out = (float*)d_out;          // [logits(50000) | h_new(512) | h3_new(512)]

    kA<<<256, 128, 0, stream>>>(intervalX, h3, W_h3, b_h3, W_int, b_int, out);
    kB<<<512, 1024, 0, stream>>>(inputX, emb, h, W_ctx, b_ctx, out + V + H,
                                 Wx, Bx, b_ictx, out);
    kC<<<6250, 256, 0, stream>>>(out + V, fc_W, fc_b, out);
}